// Round 2
// baseline (10923.194 us; speedup 1.0000x reference)
//
#include <hip/hip_runtime.h>
#include <hip/hip_cooperative_groups.h>
#include <cstdint>
#include <cstddef>

namespace cg = cooperative_groups;

#define DEVINL __device__ __forceinline__

typedef __attribute__((ext_vector_type(8))) short bf16x8;
typedef __attribute__((ext_vector_type(4))) float f32x4;
typedef __attribute__((ext_vector_type(4))) unsigned short u16x4;

// ---------- workspace layout ----------
static constexpr size_t OFF_XB   = 0;                              // x bf16 [32768][1024]
static constexpr size_t OFF_WHT  = OFF_XB  + (size_t)32768*1024*2; // Wh^T bf16 [4096][1024]
static constexpr size_t OFF_WXT  = OFF_WHT + (size_t)4096*1024*2;  // Wx^T bf16 [4096][1024]
static constexpr size_t OFF_WCT  = OFF_WXT + (size_t)4096*1024*2;  // Wc^T bf16 [1024][1024]
static constexpr size_t OFF_BIAS = OFF_WCT + (size_t)1024*1024*2;  // bias_all f32 [4096]
static constexpr size_t OFF_XW   = OFF_BIAS + 4096*4;              // XW bf16 [32768][4096]
static constexpr size_t OFF_H    = OFF_XW  + (size_t)32768*4096*2; // h bf16 [32768][1024]
static constexpr size_t OFF_CB   = OFF_H   + (size_t)32768*1024*2; // cell bf16 x2 [128][1024]
static constexpr size_t WS_NEEDED = OFF_CB + (size_t)2*128*1024*2;

// ---------- helpers ----------
DEVINL unsigned short f2b(float f) {
  union { float f; unsigned u; } v; v.f = f;
  unsigned r = (v.u + 0x7FFFu + ((v.u >> 16) & 1u)) >> 16;  // RNE
  return (unsigned short)r;
}
DEVINL float b2f(unsigned short h) {
  union { unsigned u; float f; } v; v.u = ((unsigned)h) << 16;
  return v.f;
}
DEVINL float sigmoidf_(float x) { return 1.0f / (1.0f + __expf(-x)); }
DEVINL float tanhf_(float x) { float e = __expf(2.0f * x); return 1.0f - 2.0f / (e + 1.0f); }
DEVINL f32x4 MFMA(bf16x8 a, bf16x8 b, f32x4 c) {
  return __builtin_amdgcn_mfma_f32_16x16x32_bf16(a, b, c, 0, 0, 0);
}
DEVINL void gload16(const void* g, void* l) {
  __builtin_amdgcn_global_load_lds(
      (const __attribute__((address_space(1))) void*)g,
      (__attribute__((address_space(3))) void*)l, 16, 0, 0);
}

// ---------- conversions ----------
__global__ void cvt_x_kernel(const float* __restrict__ x, unsigned short* __restrict__ xb) {
  size_t i = ((size_t)blockIdx.x * 256 + threadIdx.x) * 4;
  float4 v = *(const float4*)(x + i);
  u16x4 o; o.x = f2b(v.x); o.y = f2b(v.y); o.z = f2b(v.z); o.w = f2b(v.w);
  *(u16x4*)(xb + i) = o;
}

// Wh^T[4j+g][k] = Wg[k][j]; Wx^T[4j+g][k] = Wg[1024+k][j]; bias_all[4j+g] = b_g[j]
__global__ void cvt_w_kernel(const float* __restrict__ Wf, const float* __restrict__ Wi1,
                             const float* __restrict__ Wi2, const float* __restrict__ Wo,
                             const float* __restrict__ bf_, const float* __restrict__ bi1,
                             const float* __restrict__ bi2, const float* __restrict__ bo,
                             unsigned short* __restrict__ WhT, unsigned short* __restrict__ WxT,
                             float* __restrict__ biasAll) {
  int idx = blockIdx.x * 256 + threadIdx.x;   // 4096*1024 total
  int k = idx & 1023, gc = idx >> 10;
  int j = gc >> 2, g = gc & 3;
  const float* W = (g == 0) ? Wf : (g == 1) ? Wi1 : (g == 2) ? Wi2 : Wo;
  WhT[idx] = f2b(W[(size_t)k * 1024 + j]);
  WxT[idx] = f2b(W[(size_t)(k + 1024) * 1024 + j]);
  if (k == 0) {
    const float* bb = (g == 0) ? bf_ : (g == 1) ? bi1 : (g == 2) ? bi2 : bo;
    biasAll[gc] = bb[j];
  }
}

__global__ void cvt_wc_kernel(const float* __restrict__ Wc, unsigned short* __restrict__ WcT) {
  int idx = blockIdx.x * 256 + threadIdx.x;   // 1024*1024 total
  int k = idx & 1023, n = idx >> 10;
  WcT[idx] = f2b(Wc[(size_t)k * 1024 + n]);
}

// ---------- 128x128 bf16 GEMM, B given as B^T [N][K], C = A@B + bias ----------
template<bool OUT_F32>
__global__ __launch_bounds__(256)
void gemm_bt(const unsigned short* __restrict__ A,   // [M][K] bf16
             const unsigned short* __restrict__ Bt,  // [N][K] bf16
             const float* __restrict__ bias,         // [N] f32
             void* __restrict__ C,
             int M, int N, int K) {
  __shared__ unsigned short sA[128 * 64];
  __shared__ unsigned short sB[128 * 64];
  const int tid  = threadIdx.x;
  const int lane = tid & 63;
  const int wid  = tid >> 6;
  const int m0   = blockIdx.y * 128;
  const int n0   = blockIdx.x * 128;
  const int wm   = (wid >> 1) * 64;
  const int wn   = (wid & 1) * 64;

  f32x4 acc[4][4];
#pragma unroll
  for (int i = 0; i < 4; ++i)
#pragma unroll
    for (int j = 0; j < 4; ++j) acc[i][j] = (f32x4){0.f, 0.f, 0.f, 0.f};

  for (int k0 = 0; k0 < K; k0 += 64) {
#pragma unroll
    for (int p = 0; p < 4; ++p) {
      int t = p * 256 + tid;
      int r = t >> 3, c = t & 7;
      gload16(A  + (size_t)(m0 + r) * K + k0 + c * 8, (char*)sA + p * 4096 + wid * 1024);
      gload16(Bt + (size_t)(n0 + r) * K + k0 + c * 8, (char*)sB + p * 4096 + wid * 1024);
    }
    __syncthreads();
#pragma unroll
    for (int kk = 0; kk < 2; ++kk) {
      bf16x8 av[4], bv[4];
#pragma unroll
      for (int mi = 0; mi < 4; ++mi)
        av[mi] = *(const bf16x8*)&sA[(wm + mi * 16 + (lane & 15)) * 64 + kk * 32 + (lane >> 4) * 8];
#pragma unroll
      for (int ni = 0; ni < 4; ++ni)
        bv[ni] = *(const bf16x8*)&sB[(wn + ni * 16 + (lane & 15)) * 64 + kk * 32 + (lane >> 4) * 8];
#pragma unroll
      for (int mi = 0; mi < 4; ++mi)
#pragma unroll
        for (int ni = 0; ni < 4; ++ni)
          acc[mi][ni] = MFMA(av[mi], bv[ni], acc[mi][ni]);
    }
    __syncthreads();
  }

#pragma unroll
  for (int mi = 0; mi < 4; ++mi)
#pragma unroll
    for (int ni = 0; ni < 4; ++ni)
#pragma unroll
      for (int r = 0; r < 4; ++r) {
        int row = m0 + wm + mi * 16 + (lane >> 4) * 4 + r;
        int col = n0 + wn + ni * 16 + (lane & 15);
        float v = acc[mi][ni][r] + bias[col];
        if (OUT_F32) ((float*)C)[(size_t)row * N + col] = v;
        else ((unsigned short*)C)[(size_t)row * N + col] = f2b(v);
      }
}

// ---------- persistent cooperative recurrence ----------
// 256 WGs x 256 threads. WG (mg,cg): rows 64*mg..+64, gate-cols 32*cg..+32
// (= cell cols 8*cg..+8). Wave (mh,nh): rows 64mg+32mh..+32, gate-cols
// 32cg+16nh..+16. B fragments (WhT slice) live in 128 VGPRs for all 256
// steps; f32 cell state lives in registers (2 elems/thread, static owner).
// bf16 cell is broadcast through global (L2), double-buffered, one
// grid.sync per step.
__global__ __launch_bounds__(256, 1)
void lstm_persist(const unsigned short* __restrict__ WhT,  // [4096][1024] bf16
                  const unsigned short* __restrict__ XW,   // [32768][4096] bf16
                  unsigned short* __restrict__ H,          // [32768][1024] bf16
                  unsigned short* __restrict__ cB0,        // [128][1024] bf16
                  unsigned short* __restrict__ cB1,
                  float* __restrict__ cellOut) {           // [128][1024] f32
  cg::grid_group grid = cg::this_grid();
  __shared__ __align__(16) float sP[64 * 36];              // preact redistribute

  const int tid  = threadIdx.x;
  const int lane = tid & 63;
  const int wid  = tid >> 6;
  const int wgid = blockIdx.x;
  const int mg = wgid >> 7;       // 0..1
  const int cg_ = wgid & 127;     // 0..127
  const int mh = wid >> 1;        // 0..1
  const int nh = wid & 1;         // 0..1

  const int rowA0 = mg * 64 + mh * 32 + (lane & 15);   // +16 for mi=1
  const int koff  = (lane >> 4) * 8;
  const int gcol  = cg_ * 32 + nh * 16 + (lane & 15);

  // ---- preload step-invariant B fragments: 32 x bf16x8 = 128 VGPR ----
  bf16x8 bfr[32];
  {
    const unsigned short* bp = WhT + (size_t)gcol * 1024 + koff;
#pragma unroll
    for (int ks = 0; ks < 32; ++ks)
      bfr[ks] = *(const bf16x8*)(bp + ks * 32);
  }

  // ---- per-thread cell ownership: 2 consecutive cell cols ----
  const int b_local = tid >> 2;          // 0..63
  const int jp      = (tid & 3) * 2;     // 0,2,4,6
  const int browg   = mg * 64 + b_local; // global batch row
  float cf0 = 0.f, cf1 = 0.f;

  const unsigned short* xwp = XW + (size_t)browg * 256 * 4096 + cg_ * 32 + jp * 4;
  unsigned short* c0p = cB0 + (size_t)browg * 1024 + cg_ * 8 + jp;  // written when t odd
  unsigned short* c1p = cB1 + (size_t)browg * 1024 + cg_ * 8 + jp;  // written when t even
  unsigned short* hp  = H + (size_t)browg * 256 * 1024 + cg_ * 8 + jp;

  for (int t = 0; t < 256; ++t) {
    const unsigned short* cin = (t & 1) ? cB1 : cB0;
    unsigned short* co        = (t & 1) ? c0p : c1p;

    // prefetch this step's x-contribution (8 gate preacts = 16 B)
    bf16x8 xw = *(const bf16x8*)(xwp + (size_t)t * 4096);

    // ---- GEMM: [32 rows x 16 cols] per wave, K=1024, A from L2, B in regs
    const unsigned short* ap0 = cin + (size_t)rowA0 * 1024 + koff;
    const unsigned short* ap1 = ap0 + 16 * 1024;
    f32x4 acc0 = (f32x4){0.f, 0.f, 0.f, 0.f};
    f32x4 acc1 = (f32x4){0.f, 0.f, 0.f, 0.f};
    bf16x8 a0[32], a1[32];
#pragma unroll
    for (int ks = 0; ks < 32; ++ks) {
      a0[ks] = *(const bf16x8*)(ap0 + ks * 32);
      a1[ks] = *(const bf16x8*)(ap1 + ks * 32);
    }
#pragma unroll
    for (int ks = 0; ks < 32; ++ks) {
      acc0 = MFMA(a0[ks], bfr[ks], acc0);
      acc1 = MFMA(a1[ks], bfr[ks], acc1);
    }

    // ---- redistribute preacts through LDS ----
#pragma unroll
    for (int mi = 0; mi < 2; ++mi) {
      f32x4 v = mi ? acc1 : acc0;
#pragma unroll
      for (int r = 0; r < 4; ++r)
        sP[(mh * 32 + mi * 16 + (lane >> 4) * 4 + r) * 36 + nh * 16 + (lane & 15)] = v[r];
    }
    __syncthreads();

    float4 g0 = *(const float4*)&sP[b_local * 36 + jp * 4];
    float4 g1 = *(const float4*)&sP[b_local * 36 + jp * 4 + 4];

    // ---- elementwise for 2 cells ----
    float c2a, c2b, ha, hb;
    {
      float pf = g0.x + b2f((unsigned short)xw[0]);
      float pi = g0.y + b2f((unsigned short)xw[1]);
      float pg = g0.z + b2f((unsigned short)xw[2]);
      float po = g0.w + b2f((unsigned short)xw[3]);
      float f = sigmoidf_(pf), i1 = sigmoidf_(pi), gg = tanhf_(pg), o = sigmoidf_(po);
      c2a = cf0 * f + i1 * gg; cf0 = c2a; ha = o * tanhf_(c2a);
    }
    {
      float pf = g1.x + b2f((unsigned short)xw[4]);
      float pi = g1.y + b2f((unsigned short)xw[5]);
      float pg = g1.z + b2f((unsigned short)xw[6]);
      float po = g1.w + b2f((unsigned short)xw[7]);
      float f = sigmoidf_(pf), i1 = sigmoidf_(pi), gg = tanhf_(pg), o = sigmoidf_(po);
      c2b = cf1 * f + i1 * gg; cf1 = c2b; hb = o * tanhf_(c2b);
    }

    unsigned cw = (unsigned)f2b(c2a) | ((unsigned)f2b(c2b) << 16);
    *(unsigned*)co = cw;
    unsigned hw = (unsigned)f2b(ha) | ((unsigned)f2b(hb) << 16);
    *(unsigned*)(hp + (size_t)t * 1024) = hw;

    grid.sync();   // cell broadcast complete; also orders sP reuse
  }

  // final f32 cell state
  *(float2*)(cellOut + (size_t)browg * 1024 + cg_ * 8 + jp) = make_float2(cf0, cf1);
}

// ---------- launcher ----------
extern "C" void kernel_launch(void* const* d_in, const int* in_sizes, int n_in,
                              void* d_out, int out_size, void* d_ws, size_t ws_size,
                              hipStream_t stream) {
  const float* x   = (const float*)d_in[0];
  const float* Wf  = (const float*)d_in[1];
  const float* bfv = (const float*)d_in[2];
  const float* Wi1 = (const float*)d_in[3];
  const float* bi1 = (const float*)d_in[4];
  const float* Wi2 = (const float*)d_in[5];
  const float* bi2 = (const float*)d_in[6];
  const float* Wo  = (const float*)d_in[7];
  const float* bo  = (const float*)d_in[8];
  const float* Wc  = (const float*)d_in[9];
  const float* bc  = (const float*)d_in[10];
  float* out = (float*)d_out;

  if (ws_size < WS_NEEDED) return;  // visible failure instead of corruption

  char* ws = (char*)d_ws;
  unsigned short* xb      = (unsigned short*)(ws + OFF_XB);
  unsigned short* WhT     = (unsigned short*)(ws + OFF_WHT);
  unsigned short* WxT     = (unsigned short*)(ws + OFF_WXT);
  unsigned short* WcT     = (unsigned short*)(ws + OFF_WCT);
  float*          biasAll = (float*)(ws + OFF_BIAS);
  unsigned short* XW      = (unsigned short*)(ws + OFF_XW);
  unsigned short* H       = (unsigned short*)(ws + OFF_H);
  unsigned short* cB0     = (unsigned short*)(ws + OFF_CB);
  unsigned short* cB1     = (unsigned short*)(ws + OFF_CB + (size_t)128 * 1024 * 2);
  float*          cellOut = out + (size_t)32768 * 1024;

  hipMemsetAsync(cB0, 0, (size_t)128 * 1024 * 2, stream);

  cvt_x_kernel <<<32768, 256, 0, stream>>>(x, xb);
  cvt_w_kernel <<<16384, 256, 0, stream>>>(Wf, Wi1, Wi2, Wo, bfv, bi1, bi2, bo, WhT, WxT, biasAll);
  cvt_wc_kernel<<< 4096, 256, 0, stream>>>(Wc, WcT);

  // XW = x @ Wx_all + biases   (M=32768, N=4096, K=1024), bf16 out
  gemm_bt<false><<<dim3(32, 256), 256, 0, stream>>>(xb, WxT, biasAll, XW, 32768, 4096, 1024);

  // persistent recurrence: 256 WGs x 256 threads, cooperative
  {
    void* args[] = { (void*)&WhT, (void*)&XW, (void*)&H,
                     (void*)&cB0, (void*)&cB1, (void*)&cellOut };
    hipLaunchCooperativeKernel(lstm_persist, dim3(256), dim3(256), args, 0u, stream);
  }

  // output_sequence = h @ Wc + bc  (M=32768, N=1024, K=1024), f32 out
  gemm_bt<true><<<dim3(8, 256), 256, 0, stream>>>(H, WcT, bc, out, 32768, 1024, 1024);
}

// Round 3
// 10370.447 us; speedup vs baseline: 1.0533x; 1.0533x over previous
//
#include <hip/hip_runtime.h>
#include <cstdint>
#include <cstddef>

#define DEVINL __device__ __forceinline__

typedef __attribute__((ext_vector_type(8))) short bf16x8;
typedef __attribute__((ext_vector_type(4))) float f32x4;
typedef __attribute__((ext_vector_type(4))) unsigned short u16x4;

// ---------- workspace layout ----------
static constexpr size_t OFF_XB   = 0;                              // x bf16 [32768][1024]
static constexpr size_t OFF_WHT  = OFF_XB  + (size_t)32768*1024*2; // Wh^T bf16 [4096][1024]
static constexpr size_t OFF_WXT  = OFF_WHT + (size_t)4096*1024*2;  // Wx^T bf16 [4096][1024]
static constexpr size_t OFF_WCT  = OFF_WXT + (size_t)4096*1024*2;  // Wc^T bf16 [1024][1024]
static constexpr size_t OFF_BIAS = OFF_WCT + (size_t)1024*1024*2;  // bias_all f32 [4096]
static constexpr size_t OFF_XW   = OFF_BIAS + 4096*4;              // XW bf16 [32768][4096]
static constexpr size_t OFF_H    = OFF_XW  + (size_t)32768*4096*2; // h bf16 [32768][1024]
static constexpr size_t OFF_CB   = OFF_H   + (size_t)32768*1024*2; // cell bf16 x2 [128][1024]
static constexpr size_t OFF_BAR  = OFF_CB  + (size_t)2*128*1024*2; // barrier counter (256B block)
static constexpr size_t WS_NEEDED = OFF_BAR + 256;

// ---------- helpers ----------
DEVINL unsigned short f2b(float f) {
  union { float f; unsigned u; } v; v.f = f;
  unsigned r = (v.u + 0x7FFFu + ((v.u >> 16) & 1u)) >> 16;  // RNE
  return (unsigned short)r;
}
DEVINL float b2f(unsigned short h) {
  union { unsigned u; float f; } v; v.u = ((unsigned)h) << 16;
  return v.f;
}
DEVINL float sigmoidf_(float x) { return 1.0f / (1.0f + __expf(-x)); }
DEVINL float tanhf_(float x) { float e = __expf(2.0f * x); return 1.0f - 2.0f / (e + 1.0f); }
DEVINL f32x4 MFMA(bf16x8 a, bf16x8 b, f32x4 c) {
  return __builtin_amdgcn_mfma_f32_16x16x32_bf16(a, b, c, 0, 0, 0);
}
DEVINL void gload16(const void* g, void* l) {
  __builtin_amdgcn_global_load_lds(
      (const __attribute__((address_space(1))) void*)g,
      (__attribute__((address_space(3))) void*)l, 16, 0, 0);
}

// custom grid barrier: monotonic counter, release-add / relaxed-spin / acquire-fence
DEVINL void gridbar(unsigned* cnt, unsigned target) {
  __syncthreads();  // all lanes' prior stores issued & complete to L2
  if (threadIdx.x == 0) {
    __hip_atomic_fetch_add(cnt, 1u, __ATOMIC_RELEASE, __HIP_MEMORY_SCOPE_AGENT);
    unsigned v;
    do {
      __builtin_amdgcn_s_sleep(1);
      v = __hip_atomic_load(cnt, __ATOMIC_RELAXED, __HIP_MEMORY_SCOPE_AGENT);
    } while (v < target);
  }
  __syncthreads();
  __threadfence();  // acquire: invalidate stale cached lines before reading peers' data
}

// ---------- conversions ----------
__global__ void cvt_x_kernel(const float* __restrict__ x, unsigned short* __restrict__ xb) {
  size_t i = ((size_t)blockIdx.x * 256 + threadIdx.x) * 4;
  float4 v = *(const float4*)(x + i);
  u16x4 o; o.x = f2b(v.x); o.y = f2b(v.y); o.z = f2b(v.z); o.w = f2b(v.w);
  *(u16x4*)(xb + i) = o;
}

// Wh^T[4j+g][k] = Wg[k][j]; Wx^T[4j+g][k] = Wg[1024+k][j]; bias_all[4j+g] = b_g[j]
__global__ void cvt_w_kernel(const float* __restrict__ Wf, const float* __restrict__ Wi1,
                             const float* __restrict__ Wi2, const float* __restrict__ Wo,
                             const float* __restrict__ bf_, const float* __restrict__ bi1,
                             const float* __restrict__ bi2, const float* __restrict__ bo,
                             unsigned short* __restrict__ WhT, unsigned short* __restrict__ WxT,
                             float* __restrict__ biasAll) {
  int idx = blockIdx.x * 256 + threadIdx.x;   // 4096*1024 total
  int k = idx & 1023, gc = idx >> 10;
  int j = gc >> 2, g = gc & 3;
  const float* W = (g == 0) ? Wf : (g == 1) ? Wi1 : (g == 2) ? Wi2 : Wo;
  WhT[idx] = f2b(W[(size_t)k * 1024 + j]);
  WxT[idx] = f2b(W[(size_t)(k + 1024) * 1024 + j]);
  if (k == 0) {
    const float* bb = (g == 0) ? bf_ : (g == 1) ? bi1 : (g == 2) ? bi2 : bo;
    biasAll[gc] = bb[j];
  }
}

__global__ void cvt_wc_kernel(const float* __restrict__ Wc, unsigned short* __restrict__ WcT) {
  int idx = blockIdx.x * 256 + threadIdx.x;   // 1024*1024 total
  int k = idx & 1023, n = idx >> 10;
  WcT[idx] = f2b(Wc[(size_t)k * 1024 + n]);
}

// ---------- 128x128 bf16 GEMM, B given as B^T [N][K], C = A@B + bias ----------
template<bool OUT_F32>
__global__ __launch_bounds__(256)
void gemm_bt(const unsigned short* __restrict__ A,   // [M][K] bf16
             const unsigned short* __restrict__ Bt,  // [N][K] bf16
             const float* __restrict__ bias,         // [N] f32
             void* __restrict__ C,
             int M, int N, int K) {
  __shared__ unsigned short sA[128 * 64];
  __shared__ unsigned short sB[128 * 64];
  const int tid  = threadIdx.x;
  const int lane = tid & 63;
  const int wid  = tid >> 6;
  const int m0   = blockIdx.y * 128;
  const int n0   = blockIdx.x * 128;
  const int wm   = (wid >> 1) * 64;
  const int wn   = (wid & 1) * 64;

  f32x4 acc[4][4];
#pragma unroll
  for (int i = 0; i < 4; ++i)
#pragma unroll
    for (int j = 0; j < 4; ++j) acc[i][j] = (f32x4){0.f, 0.f, 0.f, 0.f};

  for (int k0 = 0; k0 < K; k0 += 64) {
#pragma unroll
    for (int p = 0; p < 4; ++p) {
      int t = p * 256 + tid;
      int r = t >> 3, c = t & 7;
      gload16(A  + (size_t)(m0 + r) * K + k0 + c * 8, (char*)sA + p * 4096 + wid * 1024);
      gload16(Bt + (size_t)(n0 + r) * K + k0 + c * 8, (char*)sB + p * 4096 + wid * 1024);
    }
    __syncthreads();
#pragma unroll
    for (int kk = 0; kk < 2; ++kk) {
      bf16x8 av[4], bv[4];
#pragma unroll
      for (int mi = 0; mi < 4; ++mi)
        av[mi] = *(const bf16x8*)&sA[(wm + mi * 16 + (lane & 15)) * 64 + kk * 32 + (lane >> 4) * 8];
#pragma unroll
      for (int ni = 0; ni < 4; ++ni)
        bv[ni] = *(const bf16x8*)&sB[(wn + ni * 16 + (lane & 15)) * 64 + kk * 32 + (lane >> 4) * 8];
#pragma unroll
      for (int mi = 0; mi < 4; ++mi)
#pragma unroll
        for (int ni = 0; ni < 4; ++ni)
          acc[mi][ni] = MFMA(av[mi], bv[ni], acc[mi][ni]);
    }
    __syncthreads();
  }

#pragma unroll
  for (int mi = 0; mi < 4; ++mi)
#pragma unroll
    for (int ni = 0; ni < 4; ++ni)
#pragma unroll
      for (int r = 0; r < 4; ++r) {
        int row = m0 + wm + mi * 16 + (lane >> 4) * 4 + r;
        int col = n0 + wn + ni * 16 + (lane & 15);
        float v = acc[mi][ni][r] + bias[col];
        if (OUT_F32) ((float*)C)[(size_t)row * N + col] = v;
        else ((unsigned short*)C)[(size_t)row * N + col] = f2b(v);
      }
}

// ---------- persistent recurrence, custom barrier, B staged in LDS ----------
// 256 WGs x 256 threads (cooperative, 1 WG/CU). WG (mg,cg_): rows 64*mg..+64,
// gate-cols 32*cg_..+32. Wave (mh,nh): rows 64mg+32mh..+32 (two 16-row MFMA
// tiles), gate-cols 32cg_+16nh..+16. WhT fragments staged ONCE into LDS
// (immune to the per-step L2 invalidation); cell bf16 ping-pongs through
// L3 with one custom grid barrier per step; f32 cell state in registers.
__global__ __launch_bounds__(256, 1)
void lstm_persist(const unsigned short* __restrict__ WhT,  // [4096][1024] bf16
                  const unsigned short* __restrict__ XW,   // [32768][4096] bf16
                  unsigned short* __restrict__ H,          // [32768][1024] bf16
                  unsigned short* __restrict__ cB0,        // [128][1024] bf16
                  unsigned short* __restrict__ cB1,
                  float* __restrict__ cellOut,             // [128][1024] f32
                  unsigned* __restrict__ barCnt) {
  __shared__ __align__(16) unsigned short sBF[2 * 32 * 64 * 8];  // 64 KB B fragments
  __shared__ __align__(16) float sP[64 * 36];                    // 9.2 KB preact redistribute

  const int tid  = threadIdx.x;
  const int lane = tid & 63;
  const int wid  = tid >> 6;
  const int wgid = blockIdx.x;
  const int mg = wgid >> 7;       // 0..1
  const int cg_ = wgid & 127;     // 0..127
  const int mh = wid >> 1;        // 0..1
  const int nh = wid & 1;         // 0..1

  const int rowA0 = mg * 64 + mh * 32 + (lane & 15);   // +16 for second tile
  const int koff  = (lane >> 4) * 8;
  const int gcol  = cg_ * 32 + nh * 16 + (lane & 15);

  // ---- stage step-invariant B fragments into LDS (once) ----
  {
    const unsigned short* bp = WhT + (size_t)gcol * 1024 + koff;
#pragma unroll
    for (int i = 0; i < 16; ++i) {
      int ks = mh * 16 + i;                      // waves (mh,nh) split the ks range
      bf16x8 v = *(const bf16x8*)(bp + ks * 32);
      *(bf16x8*)&sBF[((nh * 32 + ks) * 64 + lane) * 8] = v;
    }
  }
  __syncthreads();

  // ---- per-thread cell ownership: 2 consecutive cell cols ----
  const int b_local = tid >> 2;          // 0..63
  const int jp      = (tid & 3) * 2;     // 0,2,4,6
  const int browg   = mg * 64 + b_local; // global batch row
  float cf0 = 0.f, cf1 = 0.f;

  const unsigned short* xwp = XW + (size_t)browg * 256 * 4096 + cg_ * 32 + jp * 4;
  unsigned short* c0p = cB0 + (size_t)browg * 1024 + cg_ * 8 + jp;  // written when t odd
  unsigned short* c1p = cB1 + (size_t)browg * 1024 + cg_ * 8 + jp;  // written when t even
  unsigned short* hp  = H + (size_t)browg * 256 * 1024 + cg_ * 8 + jp;

  const int sBbase = (nh * 2048 + lane) * 8;     // + ks*512 per step

  for (int t = 0; t < 256; ++t) {
    const unsigned short* cin = (t & 1) ? cB1 : cB0;
    unsigned short* co        = (t & 1) ? c0p : c1p;

    // this step's x-contribution (8 gate preacts, 16 B)
    bf16x8 xw = *(const bf16x8*)(xwp + (size_t)t * 4096);

    // ---- GEMM: [32 rows x 16 cols] per wave, K=1024, A from L3, B from LDS
    const unsigned short* ap0 = cin + (size_t)rowA0 * 1024 + koff;
    const unsigned short* ap1 = ap0 + 16 * 1024;
    f32x4 acc0 = (f32x4){0.f, 0.f, 0.f, 0.f};
    f32x4 acc1 = (f32x4){0.f, 0.f, 0.f, 0.f};
#pragma unroll
    for (int ks = 0; ks < 32; ++ks) {
      bf16x8 a0 = *(const bf16x8*)(ap0 + ks * 32);
      bf16x8 a1 = *(const bf16x8*)(ap1 + ks * 32);
      bf16x8 bv = *(const bf16x8*)&sBF[sBbase + ks * 512];
      acc0 = MFMA(a0, bv, acc0);
      acc1 = MFMA(a1, bv, acc1);
    }

    // ---- redistribute preacts through LDS ----
#pragma unroll
    for (int mi = 0; mi < 2; ++mi) {
      f32x4 v = mi ? acc1 : acc0;
#pragma unroll
      for (int r = 0; r < 4; ++r)
        sP[(mh * 32 + mi * 16 + (lane >> 4) * 4 + r) * 36 + nh * 16 + (lane & 15)] = v[r];
    }
    __syncthreads();

    float4 g0 = *(const float4*)&sP[b_local * 36 + jp * 4];
    float4 g1 = *(const float4*)&sP[b_local * 36 + jp * 4 + 4];

    // ---- elementwise for 2 cells ----
    float c2a, c2b, ha, hb;
    {
      float pf = g0.x + b2f((unsigned short)xw[0]);
      float pi = g0.y + b2f((unsigned short)xw[1]);
      float pg = g0.z + b2f((unsigned short)xw[2]);
      float po = g0.w + b2f((unsigned short)xw[3]);
      float f = sigmoidf_(pf), i1 = sigmoidf_(pi), gg = tanhf_(pg), o = sigmoidf_(po);
      c2a = cf0 * f + i1 * gg; cf0 = c2a; ha = o * tanhf_(c2a);
    }
    {
      float pf = g1.x + b2f((unsigned short)xw[4]);
      float pi = g1.y + b2f((unsigned short)xw[5]);
      float pg = g1.z + b2f((unsigned short)xw[6]);
      float po = g1.w + b2f((unsigned short)xw[7]);
      float f = sigmoidf_(pf), i1 = sigmoidf_(pi), gg = tanhf_(pg), o = sigmoidf_(po);
      c2b = cf1 * f + i1 * gg; cf1 = c2b; hb = o * tanhf_(c2b);
    }

    unsigned cw = (unsigned)f2b(c2a) | ((unsigned)f2b(c2b) << 16);
    *(unsigned*)co = cw;
    unsigned hw = (unsigned)f2b(ha) | ((unsigned)f2b(hb) << 16);
    *(unsigned*)(hp + (size_t)t * 1024) = hw;

    gridbar(barCnt, (unsigned)(t + 1) * 256u);  // cell broadcast; also orders sP reuse
  }

  // final f32 cell state (kernel-end implicit release flushes it)
  *(float2*)(cellOut + (size_t)browg * 1024 + cg_ * 8 + jp) = make_float2(cf0, cf1);
}

// ---------- launcher ----------
extern "C" void kernel_launch(void* const* d_in, const int* in_sizes, int n_in,
                              void* d_out, int out_size, void* d_ws, size_t ws_size,
                              hipStream_t stream) {
  const float* x   = (const float*)d_in[0];
  const float* Wf  = (const float*)d_in[1];
  const float* bfv = (const float*)d_in[2];
  const float* Wi1 = (const float*)d_in[3];
  const float* bi1 = (const float*)d_in[4];
  const float* Wi2 = (const float*)d_in[5];
  const float* bi2 = (const float*)d_in[6];
  const float* Wo  = (const float*)d_in[7];
  const float* bo  = (const float*)d_in[8];
  const float* Wc  = (const float*)d_in[9];
  const float* bc  = (const float*)d_in[10];
  float* out = (float*)d_out;

  if (ws_size < WS_NEEDED) return;  // visible failure instead of corruption

  char* ws = (char*)d_ws;
  unsigned short* xb      = (unsigned short*)(ws + OFF_XB);
  unsigned short* WhT     = (unsigned short*)(ws + OFF_WHT);
  unsigned short* WxT     = (unsigned short*)(ws + OFF_WXT);
  unsigned short* WcT     = (unsigned short*)(ws + OFF_WCT);
  float*          biasAll = (float*)(ws + OFF_BIAS);
  unsigned short* XW      = (unsigned short*)(ws + OFF_XW);
  unsigned short* H       = (unsigned short*)(ws + OFF_H);
  unsigned short* cB0     = (unsigned short*)(ws + OFF_CB);
  unsigned short* cB1     = (unsigned short*)(ws + OFF_CB + (size_t)128 * 1024 * 2);
  unsigned*       barCnt  = (unsigned*)(ws + OFF_BAR);
  float*          cellOut = out + (size_t)32768 * 1024;

  hipMemsetAsync(cB0, 0, (size_t)128 * 1024 * 2, stream);
  hipMemsetAsync(barCnt, 0, 256, stream);   // reset barrier counter EVERY launch

  cvt_x_kernel <<<32768, 256, 0, stream>>>(x, xb);
  cvt_w_kernel <<<16384, 256, 0, stream>>>(Wf, Wi1, Wi2, Wo, bfv, bi1, bi2, bo, WhT, WxT, biasAll);
  cvt_wc_kernel<<< 4096, 256, 0, stream>>>(Wc, WcT);

  // XW = x @ Wx_all + biases   (M=32768, N=4096, K=1024), bf16 out
  gemm_bt<false><<<dim3(32, 256), 256, 0, stream>>>(xb, WxT, biasAll, XW, 32768, 4096, 1024);

  // persistent recurrence: 256 WGs x 256 threads, cooperative (residency), own barrier
  {
    void* args[] = { (void*)&WhT, (void*)&XW, (void*)&H,
                     (void*)&cB0, (void*)&cB1, (void*)&cellOut, (void*)&barCnt };
    hipLaunchCooperativeKernel(lstm_persist, dim3(256), dim3(256), args, 0u, stream);
  }

  // output_sequence = h @ Wc + bc  (M=32768, N=1024, K=1024), f32 out
  gemm_bt<true><<<dim3(8, 256), 256, 0, stream>>>(H, WcT, bc, out, 32768, 1024, 1024);
}

// Round 5
// 1791.016 us; speedup vs baseline: 6.0989x; 5.7903x over previous
//
#include <hip/hip_runtime.h>
#include <cstdint>
#include <cstddef>

#define DEVINL __device__ __forceinline__

typedef __attribute__((ext_vector_type(8))) short bf16x8;
typedef __attribute__((ext_vector_type(4))) float f32x4;
typedef __attribute__((ext_vector_type(4))) unsigned short u16x4;
typedef __attribute__((ext_vector_type(4))) unsigned int u32x4;

// ---------- workspace layout ----------
static constexpr size_t OFF_XB   = 0;                              // x bf16 [32768][1024]
static constexpr size_t OFF_WHT  = OFF_XB  + (size_t)32768*1024*2; // Wh^T bf16 [4096][1024]
static constexpr size_t OFF_WXT  = OFF_WHT + (size_t)4096*1024*2;  // Wx^T bf16 [4096][1024]
static constexpr size_t OFF_WCT  = OFF_WXT + (size_t)4096*1024*2;  // Wc^T bf16 [1024][1024]
static constexpr size_t OFF_BIAS = OFF_WCT + (size_t)1024*1024*2;  // bias_all f32 [4096]
static constexpr size_t OFF_XW   = OFF_BIAS + 4096*4;              // XW bf16 [32768][4096]
static constexpr size_t OFF_H    = OFF_XW  + (size_t)32768*4096*2; // h bf16 [32768][1024]
static constexpr size_t OFF_CB   = OFF_H   + (size_t)32768*1024*2; // cell bf16 x2 [128][1024]
static constexpr size_t OFF_BAR  = OFF_CB  + (size_t)2*128*1024*2; // barrier lines, 16 KB
static constexpr size_t WS_NEEDED = OFF_BAR + 16384;

// ---------- helpers ----------
DEVINL unsigned short f2b(float f) {
  union { float f; unsigned u; } v; v.f = f;
  unsigned r = (v.u + 0x7FFFu + ((v.u >> 16) & 1u)) >> 16;  // RNE
  return (unsigned short)r;
}
DEVINL float b2f(unsigned short h) {
  union { unsigned u; float f; } v; v.u = ((unsigned)h) << 16;
  return v.f;
}
DEVINL float sigmoidf_(float x) { return 1.0f / (1.0f + __expf(-x)); }
DEVINL float tanhf_(float x) { float e = __expf(2.0f * x); return 1.0f - 2.0f / (e + 1.0f); }
DEVINL f32x4 MFMA(bf16x8 a, bf16x8 b, f32x4 c) {
  return __builtin_amdgcn_mfma_f32_16x16x32_bf16(a, b, c, 0, 0, 0);
}
DEVINL void gload16(const void* g, void* l) {
  __builtin_amdgcn_global_load_lds(
      (const __attribute__((address_space(1))) void*)g,
      (__attribute__((address_space(3))) void*)l, 16, 0, 0);
}

// ---------- conversions ----------
__global__ void cvt_x_kernel(const float* __restrict__ x, unsigned short* __restrict__ xb) {
  size_t i = ((size_t)blockIdx.x * 256 + threadIdx.x) * 4;
  float4 v = *(const float4*)(x + i);
  u16x4 o; o.x = f2b(v.x); o.y = f2b(v.y); o.z = f2b(v.z); o.w = f2b(v.w);
  *(u16x4*)(xb + i) = o;
}

// Wh^T[4j+g][k] = Wg[k][j]; Wx^T[4j+g][k] = Wg[1024+k][j]; bias_all[4j+g] = b_g[j]
__global__ void cvt_w_kernel(const float* __restrict__ Wf, const float* __restrict__ Wi1,
                             const float* __restrict__ Wi2, const float* __restrict__ Wo,
                             const float* __restrict__ bf_, const float* __restrict__ bi1,
                             const float* __restrict__ bi2, const float* __restrict__ bo,
                             unsigned short* __restrict__ WhT, unsigned short* __restrict__ WxT,
                             float* __restrict__ biasAll) {
  int idx = blockIdx.x * 256 + threadIdx.x;   // 4096*1024 total
  int k = idx & 1023, gc = idx >> 10;
  int j = gc >> 2, g = gc & 3;
  const float* W = (g == 0) ? Wf : (g == 1) ? Wi1 : (g == 2) ? Wi2 : Wo;
  WhT[idx] = f2b(W[(size_t)k * 1024 + j]);
  WxT[idx] = f2b(W[(size_t)(k + 1024) * 1024 + j]);
  if (k == 0) {
    const float* bb = (g == 0) ? bf_ : (g == 1) ? bi1 : (g == 2) ? bi2 : bo;
    biasAll[gc] = bb[j];
  }
}

__global__ void cvt_wc_kernel(const float* __restrict__ Wc, unsigned short* __restrict__ WcT) {
  int idx = blockIdx.x * 256 + threadIdx.x;   // 1024*1024 total
  int k = idx & 1023, n = idx >> 10;
  WcT[idx] = f2b(Wc[(size_t)k * 1024 + n]);
}

// ---------- 128x128 bf16 GEMM, B given as B^T [N][K], C = A@B + bias ----------
template<bool OUT_F32>
__global__ __launch_bounds__(256)
void gemm_bt(const unsigned short* __restrict__ A,   // [M][K] bf16
             const unsigned short* __restrict__ Bt,  // [N][K] bf16
             const float* __restrict__ bias,         // [N] f32
             void* __restrict__ C,
             int M, int N, int K) {
  __shared__ unsigned short sA[128 * 64];
  __shared__ unsigned short sB[128 * 64];
  const int tid  = threadIdx.x;
  const int lane = tid & 63;
  const int wid  = tid >> 6;
  const int m0   = blockIdx.y * 128;
  const int n0   = blockIdx.x * 128;
  const int wm   = (wid >> 1) * 64;
  const int wn   = (wid & 1) * 64;

  f32x4 acc[4][4];
#pragma unroll
  for (int i = 0; i < 4; ++i)
#pragma unroll
    for (int j = 0; j < 4; ++j) acc[i][j] = (f32x4){0.f, 0.f, 0.f, 0.f};

  for (int k0 = 0; k0 < K; k0 += 64) {
#pragma unroll
    for (int p = 0; p < 4; ++p) {
      int t = p * 256 + tid;
      int r = t >> 3, c = t & 7;
      gload16(A  + (size_t)(m0 + r) * K + k0 + c * 8, (char*)sA + p * 4096 + wid * 1024);
      gload16(Bt + (size_t)(n0 + r) * K + k0 + c * 8, (char*)sB + p * 4096 + wid * 1024);
    }
    __syncthreads();
#pragma unroll
    for (int kk = 0; kk < 2; ++kk) {
      bf16x8 av[4], bv[4];
#pragma unroll
      for (int mi = 0; mi < 4; ++mi)
        av[mi] = *(const bf16x8*)&sA[(wm + mi * 16 + (lane & 15)) * 64 + kk * 32 + (lane >> 4) * 8];
#pragma unroll
      for (int ni = 0; ni < 4; ++ni)
        bv[ni] = *(const bf16x8*)&sB[(wn + ni * 16 + (lane & 15)) * 64 + kk * 32 + (lane >> 4) * 8];
#pragma unroll
      for (int mi = 0; mi < 4; ++mi)
#pragma unroll
        for (int ni = 0; ni < 4; ++ni)
          acc[mi][ni] = MFMA(av[mi], bv[ni], acc[mi][ni]);
    }
    __syncthreads();
  }

#pragma unroll
  for (int mi = 0; mi < 4; ++mi)
#pragma unroll
    for (int ni = 0; ni < 4; ++ni)
#pragma unroll
      for (int r = 0; r < 4; ++r) {
        int row = m0 + wm + mi * 16 + (lane >> 4) * 4 + r;
        int col = n0 + wn + ni * 16 + (lane & 15);
        float v = acc[mi][ni][r] + bias[col];
        if (OUT_F32) ((float*)C)[(size_t)row * N + col] = v;
        else ((unsigned short*)C)[(size_t)row * N + col] = f2b(v);
      }
}

// ---------- persistent recurrence v5: fence-free MALL protocol ----------
// 256 WGs x 256 threads (cooperative for co-residency; own barrier).
// WG (mq, cs): mq = wgid&3 -> batch rows 32*mq..+32 (4 independent quarters);
// cs = wgid>>2 -> gate-cols 64*cs..+64 (= cell cols 16*cs..+16). Wave nh:
// gate-cols 64cs+16nh..+16, both 16-row m-tiles.
// COHERENCE: cell bf16 stores = relaxed agent atomic (write-through to MALL);
// cell loads = sc0|sc1 flagged asm loads (bypass L1/L2, read MALL). H = plain
// cached (flushed at kernel end). NO buffer_inv / wbl2 anywhere -> no dirty-
// line-drop hazard, no per-step L2 invalidation. Barrier = per-quarter 2-level
// tree (8 groups x 8 WGs), all relaxed, tid0 only; ordering from __syncthreads
// vmcnt drain + control dependence on the spin.
__global__ __launch_bounds__(256, 1)
void lstm_persist(const unsigned short* __restrict__ WhT,  // [4096][1024] bf16
                  const unsigned short* __restrict__ XW,   // [32768][4096] bf16
                  unsigned short* __restrict__ H,          // [32768][1024] bf16
                  unsigned short* __restrict__ cB0,        // [128][1024] bf16
                  unsigned short* __restrict__ cB1,
                  float* __restrict__ cellOut,             // [128][1024] f32
                  unsigned* __restrict__ bar) {
  __shared__ __align__(16) char  sA[32 * 2064];   // 66 KB, row stride 2064B (pad kills bank conflicts)
  __shared__ __align__(16) float sP[32 * 68];     // 8.7 KB preact redistribute

  const int tid  = threadIdx.x;
  const int lane = tid & 63;
  const int nh   = tid >> 6;       // wave id = n-tile
  const int wgid = blockIdx.x;
  const int mq   = wgid & 3;       // row quarter
  const int cs   = wgid >> 2;      // col slice 0..63
  const int grp  = cs >> 3;        // group 0..7 within quarter

  // barrier lines (64-u32 = 256B spacing; disjoint: qc 0..255, qf 1024..1279, gcnt 2048..4095)
  unsigned* qc   = bar + mq * 64;
  unsigned* qf   = bar + 1024 + mq * 64;
  unsigned* gcnt = bar + 2048 + (mq * 8 + grp) * 64;

  const int r0 = lane & 15;        // row within m-tile
  const int ch = lane >> 4;        // 16B chunk id within K-slice

  // ---- Wh fragments in registers: volatile loads (non-remat), 128 VGPR ----
  bf16x8 bfr[32];
  {
    const unsigned short* bp = WhT + (size_t)(cs * 64 + nh * 16 + r0) * 1024 + ch * 8;
#pragma unroll
    for (int ks = 0; ks < 32; ++ks)
      bfr[ks] = *(const volatile bf16x8*)(bp + ks * 32);
  }

  // ---- per-thread cell ownership: 2 consecutive cell cols ----
  const int b_local = tid >> 3;          // 0..31
  const int jp      = (tid & 7) * 2;     // 0,2,..,14
  const int browg   = mq * 32 + b_local; // global batch row
  float cf0 = 0.f, cf1 = 0.f;

  const unsigned short* xwp = XW + (size_t)browg * 256 * 4096 + cs * 64 + jp * 4;
  unsigned* c0p = (unsigned*)(cB0 + (size_t)browg * 1024 + cs * 16 + jp);
  unsigned* c1p = (unsigned*)(cB1 + (size_t)browg * 1024 + cs * 16 + jp);
  unsigned short* hp = H + (size_t)browg * 256 * 1024 + cs * 16 + jp;

  // staging geometry: thread covers rows {2it+strow}, 16B chunk stcc
  const int strow = tid >> 7;            // 0..1
  const int stcc  = tid & 127;           // 0..127

  for (int t = 0; t < 256; ++t) {
    const unsigned short* cinq = ((t & 1) ? cB1 : cB0) + (size_t)mq * 32 * 1024;

    // x-contribution for this step (8 gate preacts, 16B, plain cached: XW is read-only)
    bf16x8 xw = *(const bf16x8*)(xwp + (size_t)t * 4096);

    // ---- stage A-tile [32][1024] bf16: coherent loads -> regs -> LDS ----
    u32x4 st[16];
#pragma unroll
    for (int it = 0; it < 16; ++it) {
      const void* p = cinq + (size_t)(it * 2 + strow) * 1024 + stcc * 8;
      asm volatile("global_load_dwordx4 %0, %1, off sc0 sc1"
                   : "=&v"(st[it]) : "v"(p) : "memory");
    }
    asm volatile("s_waitcnt vmcnt(0)" ::: "memory");
    __builtin_amdgcn_sched_barrier(0);
#pragma unroll
    for (int it = 0; it < 16; ++it) {
      int r = it * 2 + strow;
      *(u32x4*)&sA[r * 2064 + stcc * 16] = st[it];
    }
    __syncthreads();

    // ---- GEMM: rows 32, cols 16 (wave's n-tile), K=1024; A LDS, B regs ----
    f32x4 acc0 = (f32x4){0.f, 0.f, 0.f, 0.f};
    f32x4 acc1 = (f32x4){0.f, 0.f, 0.f, 0.f};
#pragma unroll
    for (int ks = 0; ks < 32; ++ks) {
      bf16x8 a0 = *(const bf16x8*)&sA[r0 * 2064 + (ch + ks * 4) * 16];
      bf16x8 a1 = *(const bf16x8*)&sA[(r0 + 16) * 2064 + (ch + ks * 4) * 16];
      acc0 = MFMA(a0, bfr[ks], acc0);
      acc1 = MFMA(a1, bfr[ks], acc1);
    }

    // ---- redistribute preacts via LDS ----
#pragma unroll
    for (int rr = 0; rr < 4; ++rr) {
      sP[(ch * 4 + rr) * 68 + nh * 16 + r0]      = acc0[rr];
      sP[(ch * 4 + rr + 16) * 68 + nh * 16 + r0] = acc1[rr];
    }
    __syncthreads();

    float4 g0 = *(const float4*)&sP[b_local * 68 + jp * 4];
    float4 g1 = *(const float4*)&sP[b_local * 68 + jp * 4 + 4];

    // ---- elementwise for 2 cells ----
    float c2a, c2b, ha, hb;
    {
      float pf = g0.x + b2f((unsigned short)xw[0]);
      float pi = g0.y + b2f((unsigned short)xw[1]);
      float pg = g0.z + b2f((unsigned short)xw[2]);
      float po = g0.w + b2f((unsigned short)xw[3]);
      float f = sigmoidf_(pf), i1 = sigmoidf_(pi), gg = tanhf_(pg), o = sigmoidf_(po);
      c2a = cf0 * f + i1 * gg; cf0 = c2a; ha = o * tanhf_(c2a);
    }
    {
      float pf = g1.x + b2f((unsigned short)xw[4]);
      float pi = g1.y + b2f((unsigned short)xw[5]);
      float pg = g1.z + b2f((unsigned short)xw[6]);
      float po = g1.w + b2f((unsigned short)xw[7]);
      float f = sigmoidf_(pf), i1 = sigmoidf_(pi), gg = tanhf_(pg), o = sigmoidf_(po);
      c2b = cf1 * f + i1 * gg; cf1 = c2b; hb = o * tanhf_(c2b);
    }

    // cell: agent-scope atomic store (write-through to MALL, chip-coherent)
    unsigned cw = (unsigned)f2b(c2a) | ((unsigned)f2b(c2b) << 16);
    __hip_atomic_store((t & 1) ? c0p : c1p, cw,
                       __ATOMIC_RELAXED, __HIP_MEMORY_SCOPE_AGENT);
    // h: plain cached store (consumed after kernel end; nothing invalidates it now)
    unsigned hw = (unsigned)f2b(ha) | ((unsigned)f2b(hb) << 16);
    *(unsigned*)(hp + (size_t)t * 1024) = hw;

    // ---- per-quarter 2-level tree barrier (all relaxed, no fences) ----
    __syncthreads();   // vmcnt drain: this WG's cell stores are at MALL
    if (tid == 0) {
      unsigned tgt = 8u * (unsigned)(t + 1);
      unsigned n = __hip_atomic_fetch_add(gcnt, 1u, __ATOMIC_RELAXED,
                                          __HIP_MEMORY_SCOPE_AGENT);
      if (n == tgt - 1u) {           // last of the 8-WG group
        unsigned m = __hip_atomic_fetch_add(qc, 1u, __ATOMIC_RELAXED,
                                            __HIP_MEMORY_SCOPE_AGENT);
        if (m == tgt - 1u)           // last of the 8 groups
          __hip_atomic_store(qf, (unsigned)(t + 1),
                             __ATOMIC_RELAXED, __HIP_MEMORY_SCOPE_AGENT);
      }
      while (__hip_atomic_load(qf, __ATOMIC_RELAXED, __HIP_MEMORY_SCOPE_AGENT)
             < (unsigned)(t + 1))
        __builtin_amdgcn_s_sleep(2);
    }
    __syncthreads();
  }

  // final f32 cell state from registers (kernel-end flush covers it)
  *(float2*)(cellOut + (size_t)browg * 1024 + cs * 16 + jp) = make_float2(cf0, cf1);
}

// ---------- launcher ----------
extern "C" void kernel_launch(void* const* d_in, const int* in_sizes, int n_in,
                              void* d_out, int out_size, void* d_ws, size_t ws_size,
                              hipStream_t stream) {
  const float* x   = (const float*)d_in[0];
  const float* Wf  = (const float*)d_in[1];
  const float* bfv = (const float*)d_in[2];
  const float* Wi1 = (const float*)d_in[3];
  const float* bi1 = (const float*)d_in[4];
  const float* Wi2 = (const float*)d_in[5];
  const float* bi2 = (const float*)d_in[6];
  const float* Wo  = (const float*)d_in[7];
  const float* bo  = (const float*)d_in[8];
  const float* Wc  = (const float*)d_in[9];
  const float* bc  = (const float*)d_in[10];
  float* out = (float*)d_out;

  if (ws_size < WS_NEEDED) return;  // visible failure instead of corruption

  char* ws = (char*)d_ws;
  unsigned short* xb      = (unsigned short*)(ws + OFF_XB);
  unsigned short* WhT     = (unsigned short*)(ws + OFF_WHT);
  unsigned short* WxT     = (unsigned short*)(ws + OFF_WXT);
  unsigned short* WcT     = (unsigned short*)(ws + OFF_WCT);
  float*          biasAll = (float*)(ws + OFF_BIAS);
  unsigned short* XW      = (unsigned short*)(ws + OFF_XW);
  unsigned short* H       = (unsigned short*)(ws + OFF_H);
  unsigned short* cB0     = (unsigned short*)(ws + OFF_CB);
  unsigned short* cB1     = (unsigned short*)(ws + OFF_CB + (size_t)128 * 1024 * 2);
  unsigned*       barLn   = (unsigned*)(ws + OFF_BAR);
  float*          cellOut = out + (size_t)32768 * 1024;

  hipMemsetAsync(cB0, 0, (size_t)128 * 1024 * 2, stream);
  hipMemsetAsync(barLn, 0, 16384, stream);    // reset barrier lines EVERY launch

  cvt_x_kernel <<<32768, 256, 0, stream>>>(x, xb);
  cvt_w_kernel <<<16384, 256, 0, stream>>>(Wf, Wi1, Wi2, Wo, bfv, bi1, bi2, bo, WhT, WxT, biasAll);
  cvt_wc_kernel<<< 4096, 256, 0, stream>>>(Wc, WcT);

  // XW = x @ Wx_all + biases   (M=32768, N=4096, K=1024), bf16 out
  gemm_bt<false><<<dim3(32, 256), 256, 0, stream>>>(xb, WxT, biasAll, XW, 32768, 4096, 1024);

  // persistent recurrence: 256 WGs x 256 threads (cooperative for co-residency)
  {
    void* args[] = { (void*)&WhT, (void*)&XW, (void*)&H,
                     (void*)&cB0, (void*)&cB1, (void*)&cellOut, (void*)&barLn };
    hipLaunchCooperativeKernel(lstm_persist, dim3(256), dim3(256), args, 0u, stream);
  }

  // output_sequence = h @ Wc + bc  (M=32768, N=1024, K=1024), f32 out
  gemm_bt<true><<<dim3(8, 256), 256, 0, stream>>>(H, WcT, bc, out, 32768, 1024, 1024);
}

// Round 7
// 1713.449 us; speedup vs baseline: 6.3750x; 1.0453x over previous
//
#include <hip/hip_runtime.h>
#include <cstdint>
#include <cstddef>

#define DEVINL __device__ __forceinline__

typedef __attribute__((ext_vector_type(8))) short bf16x8;
typedef __attribute__((ext_vector_type(4))) float f32x4;
typedef __attribute__((ext_vector_type(4))) unsigned short u16x4;
typedef __attribute__((ext_vector_type(4))) unsigned int u32x4;

// ---------- workspace layout ----------
static constexpr size_t OFF_XB   = 0;                              // x bf16 [32768][1024]
static constexpr size_t OFF_WHT  = OFF_XB  + (size_t)32768*1024*2; // Wh^T bf16 [4096][1024]
static constexpr size_t OFF_WXT  = OFF_WHT + (size_t)4096*1024*2;  // Wx^T bf16 [4096][1024]
static constexpr size_t OFF_WCT  = OFF_WXT + (size_t)4096*1024*2;  // Wc^T bf16 [1024][1024]
static constexpr size_t OFF_BIAS = OFF_WCT + (size_t)1024*1024*2;  // bias_all f32 [4096]
static constexpr size_t OFF_XW   = OFF_BIAS + 4096*4;              // XW bf16 [32768][4096]
static constexpr size_t OFF_H    = OFF_XW  + (size_t)32768*4096*2; // h bf16 [32768][1024]
static constexpr size_t OFF_CB   = OFF_H   + (size_t)32768*1024*2; // cell bf16 x2 [128][1024]
static constexpr size_t OFF_BAR  = OFF_CB  + (size_t)2*128*1024*2; // barrier lines, 16 KB
static constexpr size_t WS_NEEDED = OFF_BAR + 16384;

// ---------- helpers ----------
DEVINL unsigned short f2b(float f) {
  union { float f; unsigned u; } v; v.f = f;
  unsigned r = (v.u + 0x7FFFu + ((v.u >> 16) & 1u)) >> 16;  // RNE
  return (unsigned short)r;
}
DEVINL float b2f(unsigned short h) {
  union { unsigned u; float f; } v; v.u = ((unsigned)h) << 16;
  return v.f;
}
DEVINL float sigmoidf_(float x) { return 1.0f / (1.0f + __expf(-x)); }
DEVINL float tanhf_(float x) { float e = __expf(2.0f * x); return 1.0f - 2.0f / (e + 1.0f); }
DEVINL f32x4 MFMA(bf16x8 a, bf16x8 b, f32x4 c) {
  return __builtin_amdgcn_mfma_f32_16x16x32_bf16(a, b, c, 0, 0, 0);
}
DEVINL void gload16(const void* g, void* l) {
  __builtin_amdgcn_global_load_lds(
      (const __attribute__((address_space(1))) void*)g,
      (__attribute__((address_space(3))) void*)l, 16, 0, 0);
}

// ---------- conversions ----------
__global__ void cvt_x_kernel(const float* __restrict__ x, unsigned short* __restrict__ xb) {
  size_t i = ((size_t)blockIdx.x * 256 + threadIdx.x) * 4;
  float4 v = *(const float4*)(x + i);
  u16x4 o; o.x = f2b(v.x); o.y = f2b(v.y); o.z = f2b(v.z); o.w = f2b(v.w);
  *(u16x4*)(xb + i) = o;
}

// Wh^T[4j+g][k] = Wg[k][j]; Wx^T[4j+g][k] = Wg[1024+k][j]; bias_all[4j+g] = b_g[j]
__global__ void cvt_w_kernel(const float* __restrict__ Wf, const float* __restrict__ Wi1,
                             const float* __restrict__ Wi2, const float* __restrict__ Wo,
                             const float* __restrict__ bf_, const float* __restrict__ bi1,
                             const float* __restrict__ bi2, const float* __restrict__ bo,
                             unsigned short* __restrict__ WhT, unsigned short* __restrict__ WxT,
                             float* __restrict__ biasAll) {
  int idx = blockIdx.x * 256 + threadIdx.x;   // 4096*1024 total
  int k = idx & 1023, gc = idx >> 10;
  int j = gc >> 2, g = gc & 3;
  const float* W = (g == 0) ? Wf : (g == 1) ? Wi1 : (g == 2) ? Wi2 : Wo;
  WhT[idx] = f2b(W[(size_t)k * 1024 + j]);
  WxT[idx] = f2b(W[(size_t)(k + 1024) * 1024 + j]);
  if (k == 0) {
    const float* bb = (g == 0) ? bf_ : (g == 1) ? bi1 : (g == 2) ? bi2 : bo;
    biasAll[gc] = bb[j];
  }
}

__global__ void cvt_wc_kernel(const float* __restrict__ Wc, unsigned short* __restrict__ WcT) {
  int idx = blockIdx.x * 256 + threadIdx.x;   // 1024*1024 total
  int k = idx & 1023, n = idx >> 10;
  WcT[idx] = f2b(Wc[(size_t)k * 1024 + n]);
}

// ---------- 128x128 bf16 GEMM, B given as B^T [N][K], C = A@B + bias ----------
template<bool OUT_F32>
__global__ __launch_bounds__(256)
void gemm_bt(const unsigned short* __restrict__ A,   // [M][K] bf16
             const unsigned short* __restrict__ Bt,  // [N][K] bf16
             const float* __restrict__ bias,         // [N] f32
             void* __restrict__ C,
             int M, int N, int K) {
  __shared__ unsigned short sA[128 * 64];
  __shared__ unsigned short sB[128 * 64];
  const int tid  = threadIdx.x;
  const int lane = tid & 63;
  const int wid  = tid >> 6;
  const int m0   = blockIdx.y * 128;
  const int n0   = blockIdx.x * 128;
  const int wm   = (wid >> 1) * 64;
  const int wn   = (wid & 1) * 64;

  f32x4 acc[4][4];
#pragma unroll
  for (int i = 0; i < 4; ++i)
#pragma unroll
    for (int j = 0; j < 4; ++j) acc[i][j] = (f32x4){0.f, 0.f, 0.f, 0.f};

  for (int k0 = 0; k0 < K; k0 += 64) {
#pragma unroll
    for (int p = 0; p < 4; ++p) {
      int t = p * 256 + tid;
      int r = t >> 3, c = t & 7;
      gload16(A  + (size_t)(m0 + r) * K + k0 + c * 8, (char*)sA + p * 4096 + wid * 1024);
      gload16(Bt + (size_t)(n0 + r) * K + k0 + c * 8, (char*)sB + p * 4096 + wid * 1024);
    }
    __syncthreads();
#pragma unroll
    for (int kk = 0; kk < 2; ++kk) {
      bf16x8 av[4], bv[4];
#pragma unroll
      for (int mi = 0; mi < 4; ++mi)
        av[mi] = *(const bf16x8*)&sA[(wm + mi * 16 + (lane & 15)) * 64 + kk * 32 + (lane >> 4) * 8];
#pragma unroll
      for (int ni = 0; ni < 4; ++ni)
        bv[ni] = *(const bf16x8*)&sB[(wn + ni * 16 + (lane & 15)) * 64 + kk * 32 + (lane >> 4) * 8];
#pragma unroll
      for (int mi = 0; mi < 4; ++mi)
#pragma unroll
        for (int ni = 0; ni < 4; ++ni)
          acc[mi][ni] = MFMA(av[mi], bv[ni], acc[mi][ni]);
    }
    __syncthreads();
  }

#pragma unroll
  for (int mi = 0; mi < 4; ++mi)
#pragma unroll
    for (int ni = 0; ni < 4; ++ni)
#pragma unroll
      for (int r = 0; r < 4; ++r) {
        int row = m0 + wm + mi * 16 + (lane >> 4) * 4 + r;
        int col = n0 + wn + ni * 16 + (lane & 15);
        float v = acc[mi][ni][r] + bias[col];
        if (OUT_F32) ((float*)C)[(size_t)row * N + col] = v;
        else ((unsigned short*)C)[(size_t)row * N + col] = f2b(v);
      }
}

// ---------- persistent recurrence v7: v5 protocol, 512-thread WGs ----------
// SAME proven envelope as v5 (passed, 1181us): 256 WGs, LDS 74752B, MALL
// protocol (relaxed agent-atomic paired cell stores, sc0|sc1 asm cell loads,
// plain cached H, fence-free 2-level tree barrier). ONLY change: 512 threads
// per WG (8 waves -> 2 waves/SIMD) to hide MALL/LDS/VALU latency.
// WG (mq, cs): mq = wgid&3 -> rows 32*mq..+32 (4 independent quarters);
// cs = wgid>>2 -> gate-cols 64*cs..+64. Wave (mh,nh): mh=wid>>2 (m-tile),
// nh=wid&3 (n-tile); one 16x16 MFMA tile per wave, 32 MFMA/step.
// Elementwise runs on threads 0..255 with v5's exact 2-cell code path.
__global__ __launch_bounds__(512, 2)
void lstm_persist(const unsigned short* __restrict__ WhT,  // [4096][1024] bf16
                  const unsigned short* __restrict__ XW,   // [32768][4096] bf16
                  unsigned short* __restrict__ H,          // [32768][1024] bf16
                  unsigned short* __restrict__ cB0,        // [128][1024] bf16
                  unsigned short* __restrict__ cB1,
                  float* __restrict__ cellOut,             // [128][1024] f32
                  unsigned* __restrict__ bar) {
  __shared__ __align__(16) char  sA[32 * 2064];   // 66 KB A-tile, padded stride
  __shared__ __align__(16) float sP[32 * 68];     // 8.7 KB preact redistribute

  const int tid  = threadIdx.x;
  const int lane = tid & 63;
  const int wid  = tid >> 6;       // 0..7
  const int mh   = wid >> 2;       // m-tile 0..1
  const int nh   = wid & 3;        // n-tile 0..3
  const int wgid = blockIdx.x;
  const int mq   = wgid & 3;       // row quarter
  const int cs   = wgid >> 2;      // col slice 0..63
  const int grp  = cs >> 3;        // subgroup 0..7 within quarter

  // barrier lines (256B spacing; disjoint regions) — identical to v5
  unsigned* qc   = bar + mq * 64;
  unsigned* qf   = bar + 1024 + mq * 64;
  unsigned* gcnt = bar + 2048 + (mq * 8 + grp) * 64;

  const int r0 = lane & 15;        // row/col within tile
  const int ch = lane >> 4;        // 16B chunk id within K-slice

  // ---- Wh fragments in registers: volatile loads (non-remat), 128 regs ----
  bf16x8 bfr[32];
  {
    const unsigned short* bp = WhT + (size_t)(cs * 64 + nh * 16 + r0) * 1024 + ch * 8;
#pragma unroll
    for (int ks = 0; ks < 32; ++ks)
      bfr[ks] = *(const volatile bf16x8*)(bp + ks * 32);
  }

  // ---- per-thread cell ownership (threads 0..255 only): 2 cell cols ----
  const int b_local = (tid & 255) >> 3;  // 0..31
  const int jp      = (tid & 7) * 2;     // 0,2,..,14
  const int browg   = mq * 32 + b_local; // global batch row
  float cf0 = 0.f, cf1 = 0.f;

  const unsigned short* xwp = XW + (size_t)browg * 256 * 4096 + cs * 64 + jp * 4;
  unsigned* c0p = (unsigned*)(cB0 + (size_t)browg * 1024 + cs * 16 + jp);
  unsigned* c1p = (unsigned*)(cB1 + (size_t)browg * 1024 + cs * 16 + jp);
  unsigned short* hp = H + (size_t)browg * 256 * 1024 + cs * 16 + jp;

  // staging geometry: thread covers rows {4it+strow}, 16B chunk stcc
  const int strow = tid >> 7;            // 0..3
  const int stcc  = tid & 127;           // 0..127

  for (int t = 0; t < 256; ++t) {
    const unsigned short* cinq = ((t & 1) ? cB1 : cB0) + (size_t)mq * 32 * 1024;

    // x-contribution (8 gate preacts, 16B) — load EARLY to overlap (tid<256)
    bf16x8 xw;
    if (tid < 256) xw = *(const bf16x8*)(xwp + (size_t)t * 4096);

    // ---- stage A-tile [32][1024] bf16: coherent loads -> regs -> LDS ----
    u32x4 st[8];
#pragma unroll
    for (int it = 0; it < 8; ++it) {
      const void* p = cinq + (size_t)(it * 4 + strow) * 1024 + stcc * 8;
      asm volatile("global_load_dwordx4 %0, %1, off sc0 sc1"
                   : "=&v"(st[it]) : "v"(p) : "memory");
    }
    asm volatile("s_waitcnt vmcnt(0)" ::: "memory");
    __builtin_amdgcn_sched_barrier(0);
#pragma unroll
    for (int it = 0; it < 8; ++it) {
      int r = it * 4 + strow;
      *(u32x4*)&sA[r * 2064 + stcc * 16] = st[it];
    }
    __syncthreads();

    // ---- GEMM: one 16x16 tile per wave, K=1024; A LDS, B regs ----
    f32x4 acc = (f32x4){0.f, 0.f, 0.f, 0.f};
#pragma unroll
    for (int ks = 0; ks < 32; ++ks) {
      bf16x8 a0 = *(const bf16x8*)&sA[(mh * 16 + r0) * 2064 + (ch + ks * 4) * 16];
      acc = MFMA(a0, bfr[ks], acc);
    }

    // ---- redistribute preacts via LDS ----
#pragma unroll
    for (int rr = 0; rr < 4; ++rr)
      sP[(mh * 16 + ch * 4 + rr) * 68 + nh * 16 + r0] = acc[rr];
    __syncthreads();

    if (tid < 256) {
      float4 g0 = *(const float4*)&sP[b_local * 68 + jp * 4];
      float4 g1 = *(const float4*)&sP[b_local * 68 + jp * 4 + 4];

      // ---- elementwise for 2 cells (v5's exact path) ----
      float c2a, c2b, ha, hb;
      {
        float pf = g0.x + b2f((unsigned short)xw[0]);
        float pi = g0.y + b2f((unsigned short)xw[1]);
        float pg = g0.z + b2f((unsigned short)xw[2]);
        float po = g0.w + b2f((unsigned short)xw[3]);
        float f = sigmoidf_(pf), i1 = sigmoidf_(pi), gg = tanhf_(pg), o = sigmoidf_(po);
        c2a = cf0 * f + i1 * gg; cf0 = c2a; ha = o * tanhf_(c2a);
      }
      {
        float pf = g1.x + b2f((unsigned short)xw[4]);
        float pi = g1.y + b2f((unsigned short)xw[5]);
        float pg = g1.z + b2f((unsigned short)xw[6]);
        float po = g1.w + b2f((unsigned short)xw[7]);
        float f = sigmoidf_(pf), i1 = sigmoidf_(pi), gg = tanhf_(pg), o = sigmoidf_(po);
        c2b = cf1 * f + i1 * gg; cf1 = c2b; hb = o * tanhf_(c2b);
      }

      // cell: agent-scope atomic store (write-through to MALL, chip-coherent)
      unsigned cw = (unsigned)f2b(c2a) | ((unsigned)f2b(c2b) << 16);
      __hip_atomic_store((t & 1) ? c0p : c1p, cw,
                         __ATOMIC_RELAXED, __HIP_MEMORY_SCOPE_AGENT);
      // h: plain cached store (consumed after kernel end)
      unsigned hw = (unsigned)f2b(ha) | ((unsigned)f2b(hb) << 16);
      *(unsigned*)(hp + (size_t)t * 1024) = hw;
    }

    // ---- per-quarter 2-level tree barrier (all relaxed, no fences) ----
    __syncthreads();   // vmcnt drain: this WG's cell stores are at MALL
    if (tid == 0) {
      unsigned tgt = 8u * (unsigned)(t + 1);
      unsigned n = __hip_atomic_fetch_add(gcnt, 1u, __ATOMIC_RELAXED,
                                          __HIP_MEMORY_SCOPE_AGENT);
      if (n == tgt - 1u) {           // last of the 8-WG subgroup
        unsigned m = __hip_atomic_fetch_add(qc, 1u, __ATOMIC_RELAXED,
                                            __HIP_MEMORY_SCOPE_AGENT);
        if (m == tgt - 1u)           // last of the 8 subgroups
          __hip_atomic_store(qf, (unsigned)(t + 1),
                             __ATOMIC_RELAXED, __HIP_MEMORY_SCOPE_AGENT);
      }
      while (__hip_atomic_load(qf, __ATOMIC_RELAXED, __HIP_MEMORY_SCOPE_AGENT)
             < (unsigned)(t + 1))
        __builtin_amdgcn_s_sleep(1);
    }
    __syncthreads();
  }

  // final f32 cell state from registers (kernel-end flush covers it)
  if (tid < 256)
    *(float2*)(cellOut + (size_t)browg * 1024 + cs * 16 + jp) = make_float2(cf0, cf1);
}

// ---------- launcher ----------
extern "C" void kernel_launch(void* const* d_in, const int* in_sizes, int n_in,
                              void* d_out, int out_size, void* d_ws, size_t ws_size,
                              hipStream_t stream) {
  const float* x   = (const float*)d_in[0];
  const float* Wf  = (const float*)d_in[1];
  const float* bfv = (const float*)d_in[2];
  const float* Wi1 = (const float*)d_in[3];
  const float* bi1 = (const float*)d_in[4];
  const float* Wi2 = (const float*)d_in[5];
  const float* bi2 = (const float*)d_in[6];
  const float* Wo  = (const float*)d_in[7];
  const float* bo  = (const float*)d_in[8];
  const float* Wc  = (const float*)d_in[9];
  const float* bc  = (const float*)d_in[10];
  float* out = (float*)d_out;

  if (ws_size < WS_NEEDED) return;  // visible failure instead of corruption

  char* ws = (char*)d_ws;
  unsigned short* xb      = (unsigned short*)(ws + OFF_XB);
  unsigned short* WhT     = (unsigned short*)(ws + OFF_WHT);
  unsigned short* WxT     = (unsigned short*)(ws + OFF_WXT);
  unsigned short* WcT     = (unsigned short*)(ws + OFF_WCT);
  float*          biasAll = (float*)(ws + OFF_BIAS);
  unsigned short* XW      = (unsigned short*)(ws + OFF_XW);
  unsigned short* H       = (unsigned short*)(ws + OFF_H);
  unsigned short* cB0     = (unsigned short*)(ws + OFF_CB);
  unsigned short* cB1     = (unsigned short*)(ws + OFF_CB + (size_t)128 * 1024 * 2);
  unsigned*       barLn   = (unsigned*)(ws + OFF_BAR);
  float*          cellOut = out + (size_t)32768 * 1024;

  hipMemsetAsync(cB0, 0, (size_t)128 * 1024 * 2, stream);
  hipMemsetAsync(barLn, 0, 16384, stream);    // reset barrier lines EVERY launch

  cvt_x_kernel <<<32768, 256, 0, stream>>>(x, xb);
  cvt_w_kernel <<<16384, 256, 0, stream>>>(Wf, Wi1, Wi2, Wo, bfv, bi1, bi2, bo, WhT, WxT, biasAll);
  cvt_wc_kernel<<< 4096, 256, 0, stream>>>(Wc, WcT);

  // XW = x @ Wx_all + biases   (M=32768, N=4096, K=1024), bf16 out
  gemm_bt<false><<<dim3(32, 256), 256, 0, stream>>>(xb, WxT, biasAll, XW, 32768, 4096, 1024);

  // persistent recurrence: 256 WGs x 512 threads (proven 256-WG envelope)
  {
    void* args[] = { (void*)&WhT, (void*)&XW, (void*)&H,
                     (void*)&cB0, (void*)&cB1, (void*)&cellOut, (void*)&barLn };
    hipLaunchCooperativeKernel(lstm_persist, dim3(256), dim3(512), args, 0u, stream);
  }

  // output_sequence = h @ Wc + bc  (M=32768, N=1024, K=1024), f32 out
  gemm_bt<true><<<dim3(8, 256), 256, 0, stream>>>(H, WcT, bc, out, 32768, 1024, 1024);
}